// Round 9
// baseline (259.059 us; speedup 1.0000x reference)
//
#include <hip/hip_runtime.h>
#include <hip/hip_bf16.h>

typedef __attribute__((ext_vector_type(8))) short short8;
typedef __attribute__((ext_vector_type(4))) short short4v;
typedef __attribute__((ext_vector_type(4))) float f32x4;

__device__ inline short f2bf(float f) {
  __hip_bfloat16 h = __float2bfloat16(f);
  return __builtin_bit_cast(short, h);
}

__device__ inline f32x4 mfma16(short8 a, short8 b, f32x4 c) {
  return __builtin_amdgcn_mfma_f32_16x16x32_bf16(a, b, c, 0, 0, 0);
}

// ---------------- constants ----------------
#define Bsz 16
#define Cc 128
#define HW 1024
#define NHh 4
#define CONDc 32
#define KIN 160      // C + COND
#define KOUT 512     // C * NH
#define CH3 768      // (NH+2)*C
// 1/sqrt(128) * log2(e): QK^T scores in log2 domain -> P = exp2(s - m)
#define SCALE_Q2 0.12751742f

// ---------------- merged: groupnorm stats + weight transpose/bf16 ----------------
__global__ __launch_bounds__(256) void k_pre(
    const float* __restrict__ x,
    const float* __restrict__ W0, const float* __restrict__ W1,
    const float* __restrict__ W2, const float* __restrict__ W3,
    short* __restrict__ Wt0, short* __restrict__ Wt1,
    short* __restrict__ Wt2, short* __restrict__ Wt3,
    float* __restrict__ stats) {
  int bx = blockIdx.x;
  if (bx < 512) {
    int b = bx >> 5, g = bx & 31;
    int tid = threadIdx.x, lane = tid & 63, wid = tid >> 6;
    long base = ((long)b * Cc + g * 4) * HW;
    float s = 0.f, sq = 0.f;
#pragma unroll
    for (int i = 0; i < 16; i++) {
      float v = x[base + tid + i * 256];
      s += v; sq += v * v;
    }
#pragma unroll
    for (int d = 1; d < 64; d <<= 1) {
      s += __shfl_xor(s, d);
      sq += __shfl_xor(sq, d);
    }
    __shared__ float ls[8];
    if (lane == 0) { ls[wid] = s; ls[wid + 4] = sq; }
    __syncthreads();
    if (tid == 0) {
      float ts = ls[0] + ls[1] + ls[2] + ls[3];
      float tq = ls[4] + ls[5] + ls[6] + ls[7];
      float mu = ts / 4096.f;
      float var = tq / 4096.f - mu * mu;
      var = var < 0.f ? 0.f : var;
      stats[(b * 32 + g) * 2] = mu;
      stats[(b * 32 + g) * 2 + 1] = rsqrtf(var + 1e-6f);
    }
  } else {
    int i = (bx - 512) * 256 + threadIdx.x;
    if (i < KOUT * KIN) {
      int ko = i / KIN, c = i % KIN;
      Wt0[i] = f2bf(W0[c * KOUT + ko]);
      Wt1[i] = f2bf(W1[c * KOUT + ko]);
      Wt2[i] = f2bf(W2[c * KOUT + ko]);
    }
    if (i < Cc * CH3) {
      int ko = i / CH3, ch = i % CH3;
      Wt3[i] = f2bf(W3[ch * Cc + ko]);
    }
  }
}

// ---------------- GN apply + concat conds + transpose -> XqT/XkT [b][hw][160] bf16 ----------------
__global__ __launch_bounds__(256) void k_build_xt(
    const float* __restrict__ x, const float* __restrict__ q_cond,
    const float* __restrict__ k_a, const float* __restrict__ k_b,
    const float* __restrict__ gsc, const float* __restrict__ gbi,
    const float* __restrict__ stats,
    short* __restrict__ XqT, short* __restrict__ XkT) {
  int b = blockIdx.y, hw0 = blockIdx.x * 64, tid = threadIdx.x;
  __shared__ short xq[64][KIN];
  __shared__ short xk[64][KIN];
#pragma unroll
  for (int i = 0; i < 8; i++) {
    int ci = tid + i * 256;
    int c = ci >> 4, hwo = (ci & 15) * 4;
    float4 xv = *(const float4*)(x + ((long)b * Cc + c) * HW + hw0 + hwo);
    int g = c >> 2;
    float mu = stats[(b * 32 + g) * 2];
    float rs = stats[(b * 32 + g) * 2 + 1];
    float sc = gsc[c] * rs;
    float bi = gbi[c] - mu * sc;
    short v0 = f2bf(xv.x * sc + bi);
    short v1 = f2bf(xv.y * sc + bi);
    short v2 = f2bf(xv.z * sc + bi);
    short v3 = f2bf(xv.w * sc + bi);
    xq[hwo + 0][c] = v0; xk[hwo + 0][c] = v0;
    xq[hwo + 1][c] = v1; xk[hwo + 1][c] = v1;
    xq[hwo + 2][c] = v2; xk[hwo + 2][c] = v2;
    xq[hwo + 3][c] = v3; xk[hwo + 3][c] = v3;
  }
#pragma unroll
  for (int i = 0; i < 2; i++) {
    int ci = tid + i * 256;
    int cc = ci >> 4, hwo = (ci & 15) * 4;
    long src = ((long)(b >> 1) * CONDc + cc) * HW + hw0 + hwo;
    float4 qv = *(const float4*)(q_cond + src);
    const float* ks = (b & 1) ? k_b : k_a;
    float4 kv = *(const float4*)(ks + src);
    xq[hwo + 0][Cc + cc] = f2bf(qv.x); xk[hwo + 0][Cc + cc] = f2bf(kv.x);
    xq[hwo + 1][Cc + cc] = f2bf(qv.y); xk[hwo + 1][Cc + cc] = f2bf(kv.y);
    xq[hwo + 2][Cc + cc] = f2bf(qv.z); xk[hwo + 2][Cc + cc] = f2bf(kv.z);
    xq[hwo + 3][Cc + cc] = f2bf(qv.w); xk[hwo + 3][Cc + cc] = f2bf(kv.w);
  }
  __syncthreads();
#pragma unroll
  for (int i = 0; i < 5; i++) {
    int ci = tid + i * 256;
    int row = ci / 20, ch = (ci % 20) * 8;
    long dst = ((long)b * HW + hw0 + row) * KIN + ch;
    *(short8*)(XqT + dst) = *(const short8*)(&xq[row][ch]);
    *(short8*)(XkT + dst) = *(const short8*)(&xk[row][ch]);
  }
}

// ---------------- merged QKV GEMM ----------------
__device__ inline int gswz(int row, int kb) {
  return row * 64 + (kb ^ (((row >> 1) & 3) << 4));
}

__global__ __launch_bounds__(256) void k_gemm_qkv(
    const short* __restrict__ XqT, const short* __restrict__ XkT,
    const short* __restrict__ Wt0, const short* __restrict__ Wt1,
    const short* __restrict__ Wt2,
    const float* __restrict__ b0v, const float* __restrict__ b1v,
    const float* __restrict__ b2v,
    short* __restrict__ qTb, short* __restrict__ kTb, short* __restrict__ vb) {
  int z = blockIdx.z, which = z >> 4, b = z & 15;
  const short* A;
  const short* Bm;
  short* D;
  const float* bias;
  float scale = 1.f;
  int m0, n0, ldD, bias_m = 0;
  if (which == 0) {
    A = XqT + (long)b * HW * KIN; Bm = Wt0; D = qTb + (long)b * HW * KOUT;
    bias = b0v; scale = SCALE_Q2;
    m0 = blockIdx.y * 128; n0 = blockIdx.x * 128; ldD = KOUT;
  } else if (which == 1) {
    A = XkT + (long)b * HW * KIN; Bm = Wt1; D = kTb + (long)b * HW * KOUT;
    bias = b1v;
    m0 = blockIdx.y * 128; n0 = blockIdx.x * 128; ldD = KOUT;
  } else {
    A = Wt2; Bm = XkT + (long)b * HW * KIN; D = vb + (long)b * KOUT * HW;
    bias = b2v; bias_m = 1;
    m0 = blockIdx.x * 128; n0 = blockIdx.y * 128; ldD = HW;
  }
  int tid = threadIdx.x, lane = tid & 63, wid = tid >> 6;
  int wm = (wid >> 1) * 64, wn = (wid & 1) * 64;
  int lm = lane & 15, kg = lane >> 4;
  __shared__ short lA[128 * 32];
  __shared__ short lB[128 * 32];
  f32x4 acc[4][4] = {};
  for (int k0 = 0; k0 < KIN; k0 += 32) {
    __syncthreads();
#pragma unroll
    for (int i = 0; i < 2; i++) {
      int ci = tid + i * 256;
      int row = ci >> 2, kb = (ci & 3) * 16;
      *(short8*)((char*)lA + gswz(row, kb)) =
          *(const short8*)(A + (long)(m0 + row) * KIN + k0 + (kb >> 1));
      *(short8*)((char*)lB + gswz(row, kb)) =
          *(const short8*)(Bm + (long)(n0 + row) * KIN + k0 + (kb >> 1));
    }
    __syncthreads();
    short8 af[4], bfr[4];
    int kb = kg * 16;
#pragma unroll
    for (int t = 0; t < 4; t++) {
      af[t] = *(const short8*)((char*)lA + gswz(wm + t * 16 + lm, kb));
      bfr[t] = *(const short8*)((char*)lB + gswz(wn + t * 16 + lm, kb));
    }
#pragma unroll
    for (int mt = 0; mt < 4; mt++)
#pragma unroll
      for (int nt = 0; nt < 4; nt++)
        acc[mt][nt] = mfma16(af[mt], bfr[nt], acc[mt][nt]);
  }
#pragma unroll
  for (int mt = 0; mt < 4; mt++)
#pragma unroll
    for (int nt = 0; nt < 4; nt++) {
      f32x4 c = acc[mt][nt];
      int n = n0 + wn + nt * 16 + lm;
#pragma unroll
      for (int r = 0; r < 4; r++) {
        int m = m0 + wm + mt * 16 + kg * 4 + r;
        float val = c[r] + bias[bias_m ? m : n];
        val *= scale;
        D[(long)m * ldD + n] = f2bf(val);
      }
    }
}

// ---------------- final GEMM: out = x + hhT*Wt3 + b3 (f32 out) ----------------
__global__ __launch_bounds__(256) void k_gemm_final(
    const short* __restrict__ A,      // Wt3 [128][768]
    const short* __restrict__ Ball,   // hhT [16][1024][768]
    const float* __restrict__ x, const float* __restrict__ bias,
    float* __restrict__ out) {
  int b = blockIdx.z;
  const short* B = Ball + (long)b * HW * CH3;
  int m0 = blockIdx.y * 64, n0 = blockIdx.x * 64;
  int tid = threadIdx.x, lane = tid & 63, wid = tid >> 6;
  int wm = (wid >> 1) * 32, wn = (wid & 1) * 32;
  int lm = lane & 15, kg = lane >> 4;
  __shared__ short lA[64 * 32];
  __shared__ short lB[64 * 32];
  f32x4 acc[2][2] = {};
  for (int k0 = 0; k0 < CH3; k0 += 32) {
    __syncthreads();
    {
      int row = tid >> 2, kb = (tid & 3) * 16;
      *(short8*)((char*)lA + gswz(row, kb)) =
          *(const short8*)(A + (long)(m0 + row) * CH3 + k0 + (kb >> 1));
      *(short8*)((char*)lB + gswz(row, kb)) =
          *(const short8*)(B + (long)(n0 + row) * CH3 + k0 + (kb >> 1));
    }
    __syncthreads();
    short8 af[2], bfr[2];
    int kb = kg * 16;
#pragma unroll
    for (int t = 0; t < 2; t++) {
      af[t] = *(const short8*)((char*)lA + gswz(wm + t * 16 + lm, kb));
      bfr[t] = *(const short8*)((char*)lB + gswz(wn + t * 16 + lm, kb));
    }
#pragma unroll
    for (int mt = 0; mt < 2; mt++)
#pragma unroll
      for (int nt = 0; nt < 2; nt++)
        acc[mt][nt] = mfma16(af[mt], bfr[nt], acc[mt][nt]);
  }
#pragma unroll
  for (int mt = 0; mt < 2; mt++)
#pragma unroll
    for (int nt = 0; nt < 2; nt++) {
      f32x4 c = acc[mt][nt];
      int n = n0 + wn + nt * 16 + lm;
#pragma unroll
      for (int r = 0; r < 4; r++) {
        int m = m0 + wm + mt * 16 + kg * 4 + r;
        float val = c[r] + bias[m];
        long oidx = ((long)b * Cc + m) * HW + n;
        out[oidx] = x[oidx] + val;
      }
    }
}

// ---------------- fused flash attention: 4 waves x 32 q-rows, KVBLK=64 ----------------
// Single-buffered K/V LDS (48KB -> 3 blocks/CU) + reg-prefetch, 2 barriers/tile.
// Each LDS kf/vf read feeds TWO MFMAs (q-subtiles A,B).
// 768 blocks = 8 XCD groups x 12 problems x 8 q-tiles (128 q-rows/block).
__global__ __launch_bounds__(256) void k_attn(
    const short* __restrict__ qT, const short* __restrict__ kT,
    const short* __restrict__ v, short* __restrict__ hhT) {
  int flat = blockIdx.y * 8 + blockIdx.x;
  int idx = flat >> 3;
  int p = (flat & 7) * 12 + (idx >> 3);   // 12 problems per XCD
  int q0 = (idx & 7) * 128;               // 8 q-tiles of 128 rows

  int b4 = p / 24, rem = p % 24, j = rem >> 2, e = rem & 3;
  static const int qsl[6] = {0, 1, 2, 3, 0, 2};
  static const int kvl[6] = {1, 0, 3, 2, 2, 0};
  int bq = b4 * 4 + qsl[j];
  int bkv = b4 * 4 + kvl[j];
  int midx = 4 * j + e;
  int bo = b4 * 4 + midx / 6;
  int chb = (midx % 6) * Cc;
  int tid = threadIdx.x, lane = tid & 63, wid = tid >> 6;
  int lm = lane & 15, kg = lane >> 4;

  __shared__ char lK[64 * 256];     // K^T tile [kv64][c128] bf16, swizzled
  __shared__ char lV[128 * 128];    // V tile [c128][kv64] bf16, swizzled
  __shared__ char lP[4][4096];      // per-wave P [q32][kv64] bf16, swizzled

  // Q fragments (B-operand), two 16-row subtiles per wave
  short8 qfA[4], qfB[4];
  const short* qbaseA =
      qT + ((long)bq * HW + q0 + wid * 32 + lm) * KOUT + e * Cc + kg * 8;
#pragma unroll
  for (int ks = 0; ks < 4; ks++) {
    qfA[ks] = *(const short8*)(qbaseA + ks * 32);
    qfB[ks] = *(const short8*)(qbaseA + 16 * KOUT + ks * 32);
  }

  // staging decomposition (256 threads, 1024 16B-chunks per K and per V tile)
  int krow[4], kcb[4], vrow[4], vkb[4];
  const short* kgsrc[4];
  const short* vgsrc[4];
#pragma unroll
  for (int i = 0; i < 4; i++) {
    int ci = tid + i * 256;
    krow[i] = ci >> 4; kcb[i] = (ci & 15) * 16;   // K: 64 rows x 256B
    vrow[i] = ci >> 3; vkb[i] = (ci & 7) * 16;    // V: 128 rows x 128B
    kgsrc[i] = kT + ((long)bkv * HW + krow[i]) * KOUT + e * Cc + (kcb[i] >> 1);
    vgsrc[i] = v + ((long)bkv * KOUT + e * Cc + vrow[i]) * HW + (vkb[i] >> 1);
  }

  // prefetch tile 0 into registers
  short8 kr[4], vr[4];
#pragma unroll
  for (int i = 0; i < 4; i++) {
    kr[i] = *(const short8*)(kgsrc[i]);
    vr[i] = *(const short8*)(vgsrc[i]);
  }

  float mA = -3e38f, mB = -3e38f, lsA = 0.f, lsB = 0.f;
  f32x4 oA[8] = {}, oB[8] = {};

  for (int kvt = 0; kvt < 16; kvt++) {
    __syncthreads();   // previous tile's LDS reads done
    // commit staged registers to LDS
#pragma unroll
    for (int i = 0; i < 4; i++) {
      *(short8*)(lK + krow[i] * 256 + (kcb[i] ^ ((krow[i] & 7) << 4))) = kr[i];
      *(short8*)(lV + vrow[i] * 128 + (vkb[i] ^ ((vrow[i] & 7) << 4))) = vr[i];
    }
    // issue next tile's loads (fly during compute below)
    if (kvt < 15) {
      int kvn = (kvt + 1) * 64;
#pragma unroll
      for (int i = 0; i < 4; i++) {
        kr[i] = *(const short8*)(kgsrc[i] + (long)kvn * KOUT);
        vr[i] = *(const short8*)(vgsrc[i] + kvn);
      }
    }
    __syncthreads();
    // S^T = K Q : D[kv][q16]x2; lane owns q-rows lm (A) and lm+16 (B)
    f32x4 sA[4] = {}, sB[4] = {};
    __builtin_amdgcn_s_setprio(1);
#pragma unroll
    for (int ks = 0; ks < 4; ks++) {
      int cbyte = ks * 64 + kg * 16;
#pragma unroll
      for (int nt = 0; nt < 4; nt++) {
        int row = nt * 16 + lm;
        short8 kf = *(const short8*)(lK + row * 256 + (cbyte ^ ((row & 7) << 4)));
        sA[nt] = mfma16(kf, qfA[ks], sA[nt]);
        sB[nt] = mfma16(kf, qfB[ks], sB[nt]);
      }
    }
    __builtin_amdgcn_s_setprio(0);
    // softmax A (lane-local, log2 domain), then P-write A
    {
      float mx = -3e38f;
#pragma unroll
      for (int nt = 0; nt < 4; nt++)
#pragma unroll
        for (int r = 0; r < 4; r++) mx = fmaxf(mx, sA[nt][r]);
      mx = fmaxf(mx, __shfl_xor(mx, 16));
      mx = fmaxf(mx, __shfl_xor(mx, 32));
      if (!__all(mx <= mA + 8.f)) {          // defer-max, wave-uniform
        float mnew = fmaxf(mA, mx);
        float corr = exp2f(mA - mnew);
        mA = mnew;
        lsA *= corr;
#pragma unroll
        for (int ct = 0; ct < 8; ct++) oA[ct] *= corr;
      }
#pragma unroll
      for (int nt = 0; nt < 4; nt++) {
        short4v pk;
#pragma unroll
        for (int r = 0; r < 4; r++) {
          float pv = exp2f(sA[nt][r] - mA);
          lsA += pv;
          pk[r] = f2bf(pv);
        }
        int kvb = (nt * 16 + kg * 4) * 2;
        *(short4v*)(lP[wid] + lm * 128 + (kvb ^ ((lm & 7) << 4))) = pk;
      }
    }
    // softmax B + P-write B (rows lm+16; (lm+16)&7 == lm&7)
    {
      float mx = -3e38f;
#pragma unroll
      for (int nt = 0; nt < 4; nt++)
#pragma unroll
        for (int r = 0; r < 4; r++) mx = fmaxf(mx, sB[nt][r]);
      mx = fmaxf(mx, __shfl_xor(mx, 16));
      mx = fmaxf(mx, __shfl_xor(mx, 32));
      if (!__all(mx <= mB + 8.f)) {
        float mnew = fmaxf(mB, mx);
        float corr = exp2f(mB - mnew);
        mB = mnew;
        lsB *= corr;
#pragma unroll
        for (int ct = 0; ct < 8; ct++) oB[ct] *= corr;
      }
#pragma unroll
      for (int nt = 0; nt < 4; nt++) {
        short4v pk;
#pragma unroll
        for (int r = 0; r < 4; r++) {
          float pv = exp2f(sB[nt][r] - mB);
          lsB += pv;
          pk[r] = f2bf(pv);
        }
        int kvb = (nt * 16 + kg * 4) * 2;
        *(short4v*)(lP[wid] + (lm + 16) * 128 + (kvb ^ ((lm & 7) << 4))) = pk;
      }
    }
    // O^T += V P : D[c128][q16]x2; vf read shared by A and B
    __builtin_amdgcn_s_setprio(1);
#pragma unroll
    for (int ks2 = 0; ks2 < 2; ks2++) {
      int kvbyte = ks2 * 64 + kg * 16;
      short8 pfA = *(const short8*)(lP[wid] + lm * 128 + (kvbyte ^ ((lm & 7) << 4)));
      short8 pfB = *(const short8*)(lP[wid] + (lm + 16) * 128 + (kvbyte ^ ((lm & 7) << 4)));
#pragma unroll
      for (int ct = 0; ct < 8; ct++) {
        int row = ct * 16 + lm;
        short8 vf = *(const short8*)(lV + row * 128 + (kvbyte ^ ((row & 7) << 4)));
        oA[ct] = mfma16(vf, pfA, oA[ct]);
        oB[ct] = mfma16(vf, pfB, oB[ct]);
      }
    }
    __builtin_amdgcn_s_setprio(0);
  }
  // epilogue: q = q0 + wid*32 + lm (A), +16 (B); c = ct*16 + kg*4 + r
  lsA += __shfl_xor(lsA, 16);
  lsA += __shfl_xor(lsA, 32);
  lsB += __shfl_xor(lsB, 16);
  lsB += __shfl_xor(lsB, 32);
  float invA = 1.f / lsA, invB = 1.f / lsB;
  long obase = ((long)bo * HW + q0 + wid * 32 + lm) * CH3 + chb + kg * 4;
#pragma unroll
  for (int ct = 0; ct < 8; ct++) {
    short4v pkA, pkB;
#pragma unroll
    for (int r = 0; r < 4; r++) {
      pkA[r] = f2bf(oA[ct][r] * invA);
      pkB[r] = f2bf(oB[ct][r] * invB);
    }
    *(short4v*)(hhT + obase + ct * 16) = pkA;
    *(short4v*)(hhT + obase + 16 * CH3 + ct * 16) = pkB;
  }
}

// ---------------- launcher ----------------
extern "C" void kernel_launch(void* const* d_in, const int* in_sizes, int n_in,
                              void* d_out, int out_size, void* d_ws, size_t ws_size,
                              hipStream_t stream) {
  const float* x      = (const float*)d_in[0];
  const float* q_cond = (const float*)d_in[1];
  const float* k_a    = (const float*)d_in[2];
  const float* k_b    = (const float*)d_in[3];
  const float* gsc    = (const float*)d_in[4];
  const float* gbi    = (const float*)d_in[5];
  const float* W0     = (const float*)d_in[6];
  const float* b0     = (const float*)d_in[7];
  const float* W1     = (const float*)d_in[8];
  const float* b1     = (const float*)d_in[9];
  const float* W2     = (const float*)d_in[10];
  const float* b2     = (const float*)d_in[11];
  const float* W3     = (const float*)d_in[12];
  const float* b3     = (const float*)d_in[13];
  float* out = (float*)d_out;

  char* ws = (char*)d_ws;
  float* stats = (float*)ws;                 ws += 4096;
  short* XqT   = (short*)ws;                 ws += (long)Bsz * HW * KIN * 2;
  short* XkT   = (short*)ws;                 ws += (long)Bsz * HW * KIN * 2;
  short* Wt0   = (short*)ws;                 ws += (long)KOUT * KIN * 2;
  short* Wt1   = (short*)ws;                 ws += (long)KOUT * KIN * 2;
  short* Wt2   = (short*)ws;                 ws += (long)KOUT * KIN * 2;
  short* Wt3   = (short*)ws;                 ws += (long)Cc * CH3 * 2;
  short* qTb   = (short*)ws;                 ws += (long)Bsz * HW * KOUT * 2;
  short* kTb   = (short*)ws;                 ws += (long)Bsz * HW * KOUT * 2;
  short* vb    = (short*)ws;                 ws += (long)Bsz * KOUT * HW * 2;
  short* hhT   = (short*)ws;                 ws += (long)Bsz * HW * CH3 * 2;

  k_pre<<<896, 256, 0, stream>>>(x, W0, W1, W2, W3, Wt0, Wt1, Wt2, Wt3, stats);
  k_build_xt<<<dim3(16, 16), 256, 0, stream>>>(x, q_cond, k_a, k_b, gsc, gbi,
                                               stats, XqT, XkT);
  k_gemm_qkv<<<dim3(4, 8, 48), 256, 0, stream>>>(
      XqT, XkT, Wt0, Wt1, Wt2, b0, b1, b2, qTb, kTb, vb);
  k_attn<<<dim3(8, 96), 256, 0, stream>>>(qTb, kTb, vb, hhT);
  k_gemm_final<<<dim3(16, 2, 16), 256, 0, stream>>>(Wt3, hhT, x, b3, out);
}

// Round 10
// 205.535 us; speedup vs baseline: 1.2604x; 1.2604x over previous
//
#include <hip/hip_runtime.h>
#include <hip/hip_bf16.h>

typedef __attribute__((ext_vector_type(8))) short short8;
typedef __attribute__((ext_vector_type(4))) short short4v;
typedef __attribute__((ext_vector_type(4))) float f32x4;

__device__ inline short f2bf(float f) {
  __hip_bfloat16 h = __float2bfloat16(f);
  return __builtin_bit_cast(short, h);
}

__device__ inline f32x4 mfma16(short8 a, short8 b, f32x4 c) {
  return __builtin_amdgcn_mfma_f32_16x16x32_bf16(a, b, c, 0, 0, 0);
}

// ---------------- constants ----------------
#define Bsz 16
#define Cc 128
#define HW 1024
#define NHh 4
#define CONDc 32
#define KIN 160      // C + COND
#define KOUT 512     // C * NH
#define CH3 768      // (NH+2)*C
// 1/sqrt(128) * log2(e): QK^T scores in log2 domain -> P = exp2(s - m)
#define SCALE_Q2 0.12751742f

// ---------------- merged: groupnorm stats + weight transpose/bf16 ----------------
__global__ __launch_bounds__(256) void k_pre(
    const float* __restrict__ x,
    const float* __restrict__ W0, const float* __restrict__ W1,
    const float* __restrict__ W2, const float* __restrict__ W3,
    short* __restrict__ Wt0, short* __restrict__ Wt1,
    short* __restrict__ Wt2, short* __restrict__ Wt3,
    float* __restrict__ stats) {
  int bx = blockIdx.x;
  if (bx < 512) {
    int b = bx >> 5, g = bx & 31;
    int tid = threadIdx.x, lane = tid & 63, wid = tid >> 6;
    long base = ((long)b * Cc + g * 4) * HW;
    float s = 0.f, sq = 0.f;
#pragma unroll
    for (int i = 0; i < 16; i++) {
      float v = x[base + tid + i * 256];
      s += v; sq += v * v;
    }
#pragma unroll
    for (int d = 1; d < 64; d <<= 1) {
      s += __shfl_xor(s, d);
      sq += __shfl_xor(sq, d);
    }
    __shared__ float ls[8];
    if (lane == 0) { ls[wid] = s; ls[wid + 4] = sq; }
    __syncthreads();
    if (tid == 0) {
      float ts = ls[0] + ls[1] + ls[2] + ls[3];
      float tq = ls[4] + ls[5] + ls[6] + ls[7];
      float mu = ts / 4096.f;
      float var = tq / 4096.f - mu * mu;
      var = var < 0.f ? 0.f : var;
      stats[(b * 32 + g) * 2] = mu;
      stats[(b * 32 + g) * 2 + 1] = rsqrtf(var + 1e-6f);
    }
  } else {
    int i = (bx - 512) * 256 + threadIdx.x;
    if (i < KOUT * KIN) {
      int ko = i / KIN, c = i % KIN;
      Wt0[i] = f2bf(W0[c * KOUT + ko]);
      Wt1[i] = f2bf(W1[c * KOUT + ko]);
      Wt2[i] = f2bf(W2[c * KOUT + ko]);
    }
    if (i < Cc * CH3) {
      int ko = i / CH3, ch = i % CH3;
      Wt3[i] = f2bf(W3[ch * Cc + ko]);
    }
  }
}

// ---------------- GN apply + concat conds + transpose -> XqT/XkT [b][hw][160] bf16 ----------------
__global__ __launch_bounds__(256) void k_build_xt(
    const float* __restrict__ x, const float* __restrict__ q_cond,
    const float* __restrict__ k_a, const float* __restrict__ k_b,
    const float* __restrict__ gsc, const float* __restrict__ gbi,
    const float* __restrict__ stats,
    short* __restrict__ XqT, short* __restrict__ XkT) {
  int b = blockIdx.y, hw0 = blockIdx.x * 64, tid = threadIdx.x;
  __shared__ short xq[64][KIN];
  __shared__ short xk[64][KIN];
#pragma unroll
  for (int i = 0; i < 8; i++) {
    int ci = tid + i * 256;
    int c = ci >> 4, hwo = (ci & 15) * 4;
    float4 xv = *(const float4*)(x + ((long)b * Cc + c) * HW + hw0 + hwo);
    int g = c >> 2;
    float mu = stats[(b * 32 + g) * 2];
    float rs = stats[(b * 32 + g) * 2 + 1];
    float sc = gsc[c] * rs;
    float bi = gbi[c] - mu * sc;
    short v0 = f2bf(xv.x * sc + bi);
    short v1 = f2bf(xv.y * sc + bi);
    short v2 = f2bf(xv.z * sc + bi);
    short v3 = f2bf(xv.w * sc + bi);
    xq[hwo + 0][c] = v0; xk[hwo + 0][c] = v0;
    xq[hwo + 1][c] = v1; xk[hwo + 1][c] = v1;
    xq[hwo + 2][c] = v2; xk[hwo + 2][c] = v2;
    xq[hwo + 3][c] = v3; xk[hwo + 3][c] = v3;
  }
#pragma unroll
  for (int i = 0; i < 2; i++) {
    int ci = tid + i * 256;
    int cc = ci >> 4, hwo = (ci & 15) * 4;
    long src = ((long)(b >> 1) * CONDc + cc) * HW + hw0 + hwo;
    float4 qv = *(const float4*)(q_cond + src);
    const float* ks = (b & 1) ? k_b : k_a;
    float4 kv = *(const float4*)(ks + src);
    xq[hwo + 0][Cc + cc] = f2bf(qv.x); xk[hwo + 0][Cc + cc] = f2bf(kv.x);
    xq[hwo + 1][Cc + cc] = f2bf(qv.y); xk[hwo + 1][Cc + cc] = f2bf(kv.y);
    xq[hwo + 2][Cc + cc] = f2bf(qv.z); xk[hwo + 2][Cc + cc] = f2bf(kv.z);
    xq[hwo + 3][Cc + cc] = f2bf(qv.w); xk[hwo + 3][Cc + cc] = f2bf(kv.w);
  }
  __syncthreads();
#pragma unroll
  for (int i = 0; i < 5; i++) {
    int ci = tid + i * 256;
    int row = ci / 20, ch = (ci % 20) * 8;
    long dst = ((long)b * HW + hw0 + row) * KIN + ch;
    *(short8*)(XqT + dst) = *(const short8*)(&xq[row][ch]);
    *(short8*)(XkT + dst) = *(const short8*)(&xk[row][ch]);
  }
}

// ---------------- merged QKV GEMM (reg-prefetch staging) ----------------
__device__ inline int gswz(int row, int kb) {
  return row * 64 + (kb ^ (((row >> 1) & 3) << 4));
}

__global__ __launch_bounds__(256) void k_gemm_qkv(
    const short* __restrict__ XqT, const short* __restrict__ XkT,
    const short* __restrict__ Wt0, const short* __restrict__ Wt1,
    const short* __restrict__ Wt2,
    const float* __restrict__ b0v, const float* __restrict__ b1v,
    const float* __restrict__ b2v,
    short* __restrict__ qTb, short* __restrict__ kTb, short* __restrict__ vb) {
  int z = blockIdx.z, which = z >> 4, b = z & 15;
  const short* A;
  const short* Bm;
  short* D;
  const float* bias;
  float scale = 1.f;
  int m0, n0, ldD, bias_m = 0;
  if (which == 0) {
    A = XqT + (long)b * HW * KIN; Bm = Wt0; D = qTb + (long)b * HW * KOUT;
    bias = b0v; scale = SCALE_Q2;
    m0 = blockIdx.y * 128; n0 = blockIdx.x * 128; ldD = KOUT;
  } else if (which == 1) {
    A = XkT + (long)b * HW * KIN; Bm = Wt1; D = kTb + (long)b * HW * KOUT;
    bias = b1v;
    m0 = blockIdx.y * 128; n0 = blockIdx.x * 128; ldD = KOUT;
  } else {
    A = Wt2; Bm = XkT + (long)b * HW * KIN; D = vb + (long)b * KOUT * HW;
    bias = b2v; bias_m = 1;
    m0 = blockIdx.x * 128; n0 = blockIdx.y * 128; ldD = HW;
  }
  int tid = threadIdx.x, lane = tid & 63, wid = tid >> 6;
  int wm = (wid >> 1) * 64, wn = (wid & 1) * 64;
  int lm = lane & 15, kg = lane >> 4;
  __shared__ short lA[128 * 32];
  __shared__ short lB[128 * 32];
  // staging decomposition: 512 chunks per operand, 2 per thread
  int row_[2], kb_[2];
  const short* asrc[2];
  const short* bsrc[2];
#pragma unroll
  for (int i = 0; i < 2; i++) {
    int ci = tid + i * 256;
    row_[i] = ci >> 2; kb_[i] = (ci & 3) * 16;
    asrc[i] = A + (long)(m0 + row_[i]) * KIN + (kb_[i] >> 1);
    bsrc[i] = Bm + (long)(n0 + row_[i]) * KIN + (kb_[i] >> 1);
  }
  short8 ar[2], br[2];
#pragma unroll
  for (int i = 0; i < 2; i++) {
    ar[i] = *(const short8*)(asrc[i]);
    br[i] = *(const short8*)(bsrc[i]);
  }
  f32x4 acc[4][4] = {};
  for (int k0 = 0; k0 < KIN; k0 += 32) {
    __syncthreads();
#pragma unroll
    for (int i = 0; i < 2; i++) {
      *(short8*)((char*)lA + gswz(row_[i], kb_[i])) = ar[i];
      *(short8*)((char*)lB + gswz(row_[i], kb_[i])) = br[i];
    }
    if (k0 + 32 < KIN) {
#pragma unroll
      for (int i = 0; i < 2; i++) {
        ar[i] = *(const short8*)(asrc[i] + k0 + 32);
        br[i] = *(const short8*)(bsrc[i] + k0 + 32);
      }
    }
    __syncthreads();
    short8 af[4], bfr[4];
    int kb = kg * 16;
#pragma unroll
    for (int t = 0; t < 4; t++) {
      af[t] = *(const short8*)((char*)lA + gswz(wm + t * 16 + lm, kb));
      bfr[t] = *(const short8*)((char*)lB + gswz(wn + t * 16 + lm, kb));
    }
#pragma unroll
    for (int mt = 0; mt < 4; mt++)
#pragma unroll
      for (int nt = 0; nt < 4; nt++)
        acc[mt][nt] = mfma16(af[mt], bfr[nt], acc[mt][nt]);
  }
#pragma unroll
  for (int mt = 0; mt < 4; mt++)
#pragma unroll
    for (int nt = 0; nt < 4; nt++) {
      f32x4 c = acc[mt][nt];
      int n = n0 + wn + nt * 16 + lm;
#pragma unroll
      for (int r = 0; r < 4; r++) {
        int m = m0 + wm + mt * 16 + kg * 4 + r;
        float val = c[r] + bias[bias_m ? m : n];
        val *= scale;
        D[(long)m * ldD + n] = f2bf(val);
      }
    }
}

// ---------------- final GEMM: out = x + hhT*Wt3 + b3 (f32 out, reg-prefetch) ----------------
__global__ __launch_bounds__(256) void k_gemm_final(
    const short* __restrict__ A,      // Wt3 [128][768]
    const short* __restrict__ Ball,   // hhT [16][1024][768]
    const float* __restrict__ x, const float* __restrict__ bias,
    float* __restrict__ out) {
  int b = blockIdx.z;
  const short* B = Ball + (long)b * HW * CH3;
  int m0 = blockIdx.y * 64, n0 = blockIdx.x * 64;
  int tid = threadIdx.x, lane = tid & 63, wid = tid >> 6;
  int wm = (wid >> 1) * 32, wn = (wid & 1) * 32;
  int lm = lane & 15, kg = lane >> 4;
  __shared__ short lA[64 * 32];
  __shared__ short lB[64 * 32];
  int row_ = tid >> 2, kb_ = (tid & 3) * 16;   // 64 rows x 4 chunks
  const short* asrc = A + (long)(m0 + row_) * CH3 + (kb_ >> 1);
  const short* bsrc = B + (long)(n0 + row_) * CH3 + (kb_ >> 1);
  short8 ar = *(const short8*)(asrc);
  short8 br = *(const short8*)(bsrc);
  f32x4 acc[2][2] = {};
  for (int k0 = 0; k0 < CH3; k0 += 32) {
    __syncthreads();
    *(short8*)((char*)lA + gswz(row_, kb_)) = ar;
    *(short8*)((char*)lB + gswz(row_, kb_)) = br;
    if (k0 + 32 < CH3) {
      ar = *(const short8*)(asrc + k0 + 32);
      br = *(const short8*)(bsrc + k0 + 32);
    }
    __syncthreads();
    short8 af[2], bfr[2];
    int kb = kg * 16;
#pragma unroll
    for (int t = 0; t < 2; t++) {
      af[t] = *(const short8*)((char*)lA + gswz(wm + t * 16 + lm, kb));
      bfr[t] = *(const short8*)((char*)lB + gswz(wn + t * 16 + lm, kb));
    }
#pragma unroll
    for (int mt = 0; mt < 2; mt++)
#pragma unroll
      for (int nt = 0; nt < 2; nt++)
        acc[mt][nt] = mfma16(af[mt], bfr[nt], acc[mt][nt]);
  }
#pragma unroll
  for (int mt = 0; mt < 2; mt++)
#pragma unroll
    for (int nt = 0; nt < 2; nt++) {
      f32x4 c = acc[mt][nt];
      int n = n0 + wn + nt * 16 + lm;
#pragma unroll
      for (int r = 0; r < 4; r++) {
        int m = m0 + wm + mt * 16 + kg * 4 + r;
        float val = c[r] + bias[m];
        long oidx = ((long)b * Cc + m) * HW + n;
        out[oidx] = x[oidx] + val;
      }
    }
}

// ---------------- fused flash attention: 8 waves, KVBLK=64, reg-prefetch (round-6 proven) ----------------
// 768 blocks = 8 XCD groups x 12 problems x 8 q-tiles (128 q-rows/block).
__global__ __launch_bounds__(512) void k_attn(
    const short* __restrict__ qT, const short* __restrict__ kT,
    const short* __restrict__ v, short* __restrict__ hhT) {
  int flat = blockIdx.y * 8 + blockIdx.x;
  int idx = flat >> 3;
  int p = (flat & 7) * 12 + (idx >> 3);   // 12 problems per XCD
  int q0 = (idx & 7) * 128;               // 8 q-tiles of 128 rows

  int b4 = p / 24, rem = p % 24, j = rem >> 2, e = rem & 3;
  static const int qsl[6] = {0, 1, 2, 3, 0, 2};
  static const int kvl[6] = {1, 0, 3, 2, 2, 0};
  int bq = b4 * 4 + qsl[j];
  int bkv = b4 * 4 + kvl[j];
  int midx = 4 * j + e;
  int bo = b4 * 4 + midx / 6;
  int chb = (midx % 6) * Cc;
  int tid = threadIdx.x, lane = tid & 63, wid = tid >> 6;
  int lm = lane & 15, kg = lane >> 4;

  __shared__ char lK[64 * 256];     // K^T tile [kv 64][c 128] bf16, swizzled
  __shared__ char lV[128 * 128];    // V tile [c 128][kv 64] bf16, swizzled
  __shared__ char lP[8][2048];      // per-wave P [q 16][kv 64] bf16, swizzled

  // Q fragments (B-operand): B[n=q][k=c]
  short8 qf[4];
  const short* qbase =
      qT + ((long)bq * HW + q0 + wid * 16 + lm) * KOUT + e * Cc + kg * 8;
#pragma unroll
  for (int ks = 0; ks < 4; ks++) qf[ks] = *(const short8*)(qbase + ks * 32);

  // staging decomposition (512 threads, 1024 16B-chunks per tile)
  int krow[2], kcb[2], vrow[2], vkb[2];
  const short* kgsrc[2];
  const short* vgsrc[2];
#pragma unroll
  for (int i = 0; i < 2; i++) {
    int ci = tid + i * 512;
    krow[i] = ci >> 4; kcb[i] = (ci & 15) * 16;           // K: 64 rows x 256B
    vrow[i] = ci >> 3; vkb[i] = (ci & 7) * 16;            // V: 128 rows x 128B
    kgsrc[i] = kT + ((long)bkv * HW + krow[i]) * KOUT + e * Cc + (kcb[i] >> 1);
    vgsrc[i] = v + ((long)bkv * KOUT + e * Cc + vrow[i]) * HW + (vkb[i] >> 1);
  }

  // prefetch tile 0 into registers
  short8 kr[2], vr[2];
#pragma unroll
  for (int i = 0; i < 2; i++) {
    kr[i] = *(const short8*)(kgsrc[i]);
    vr[i] = *(const short8*)(vgsrc[i]);
  }

  float mrow = -3e38f, lsum = 0.f;
  f32x4 oacc[8] = {};

  for (int kvt = 0; kvt < 16; kvt++) {
    __syncthreads();   // previous tile's LDS reads done
    // commit staged registers to LDS
#pragma unroll
    for (int i = 0; i < 2; i++) {
      *(short8*)(lK + krow[i] * 256 + (kcb[i] ^ ((krow[i] & 7) << 4))) = kr[i];
      *(short8*)(lV + vrow[i] * 128 + (vkb[i] ^ ((vrow[i] & 7) << 4))) = vr[i];
    }
    // issue next tile's loads (fly during compute below)
    if (kvt < 15) {
      int kvn = (kvt + 1) * 64;
#pragma unroll
      for (int i = 0; i < 2; i++) {
        kr[i] = *(const short8*)(kgsrc[i] + (long)kvn * KOUT);
        vr[i] = *(const short8*)(vgsrc[i] + kvn);
      }
    }
    __syncthreads();
    // S^T = K Q : D[kv 64][q 16]; lane owns q-row lm, kv = nt*16+kg*4+r
    f32x4 s[4] = {};
    __builtin_amdgcn_s_setprio(1);
#pragma unroll
    for (int ks = 0; ks < 4; ks++) {
      int cbyte = ks * 64 + kg * 16;
#pragma unroll
      for (int nt = 0; nt < 4; nt++) {
        int row = nt * 16 + lm;
        short8 kf = *(const short8*)(lK + row * 256 + (cbyte ^ ((row & 7) << 4)));
        s[nt] = mfma16(kf, qf[ks], s[nt]);
      }
    }
    __builtin_amdgcn_s_setprio(0);
    // lane-local online softmax (log2 domain)
    float mx = -3e38f;
#pragma unroll
    for (int nt = 0; nt < 4; nt++)
#pragma unroll
      for (int r = 0; r < 4; r++) mx = fmaxf(mx, s[nt][r]);
    mx = fmaxf(mx, __shfl_xor(mx, 16));
    mx = fmaxf(mx, __shfl_xor(mx, 32));
    if (mx > mrow + 8.f) {                   // defer-max (T13)
      float corr = exp2f(mrow - mx);
      mrow = mx;
      lsum *= corr;
#pragma unroll
      for (int ct = 0; ct < 8; ct++) oacc[ct] *= corr;
    }
#pragma unroll
    for (int nt = 0; nt < 4; nt++)
#pragma unroll
      for (int r = 0; r < 4; r++) {
        float pv = exp2f(s[nt][r] - mrow);
        s[nt][r] = pv;
        lsum += pv;
      }
    // P -> per-wave LDS [q 16][kv 64] (128B rows), swizzled
#pragma unroll
    for (int nt = 0; nt < 4; nt++) {
      short4v pk;
#pragma unroll
      for (int r = 0; r < 4; r++) pk[r] = f2bf(s[nt][r]);
      int kvb = (nt * 16 + kg * 4) * 2;
      *(short4v*)(lP[wid] + lm * 128 + (kvb ^ ((lm & 7) << 4))) = pk;
    }
    // O^T += V P : D[c 128][q 16]
    __builtin_amdgcn_s_setprio(1);
#pragma unroll
    for (int ks2 = 0; ks2 < 2; ks2++) {
      int kvbyte = ks2 * 64 + kg * 16;
      short8 pf = *(const short8*)(lP[wid] + lm * 128 + (kvbyte ^ ((lm & 7) << 4)));
#pragma unroll
      for (int ct = 0; ct < 8; ct++) {
        int row = ct * 16 + lm;
        short8 vf = *(const short8*)(lV + row * 128 + (kvbyte ^ ((row & 7) << 4)));
        oacc[ct] = mfma16(vf, pf, oacc[ct]);
      }
    }
    __builtin_amdgcn_s_setprio(0);
  }
  // epilogue
  lsum += __shfl_xor(lsum, 16);
  lsum += __shfl_xor(lsum, 32);
  float inv = 1.f / lsum;
  long obase = ((long)bo * HW + q0 + wid * 16 + lm) * CH3 + chb + kg * 4;
#pragma unroll
  for (int ct = 0; ct < 8; ct++) {
    short4v pk;
#pragma unroll
    for (int r = 0; r < 4; r++) pk[r] = f2bf(oacc[ct][r] * inv);
    *(short4v*)(hhT + obase + ct * 16) = pk;
  }
}

// ---------------- launcher ----------------
extern "C" void kernel_launch(void* const* d_in, const int* in_sizes, int n_in,
                              void* d_out, int out_size, void* d_ws, size_t ws_size,
                              hipStream_t stream) {
  const float* x      = (const float*)d_in[0];
  const float* q_cond = (const float*)d_in[1];
  const float* k_a    = (const float*)d_in[2];
  const float* k_b    = (const float*)d_in[3];
  const float* gsc    = (const float*)d_in[4];
  const float* gbi    = (const float*)d_in[5];
  const float* W0     = (const float*)d_in[6];
  const float* b0     = (const float*)d_in[7];
  const float* W1     = (const float*)d_in[8];
  const float* b1     = (const float*)d_in[9];
  const float* W2     = (const float*)d_in[10];
  const float* b2     = (const float*)d_in[11];
  const float* W3     = (const float*)d_in[12];
  const float* b3     = (const float*)d_in[13];
  float* out = (float*)d_out;

  char* ws = (char*)d_ws;
  float* stats = (float*)ws;                 ws += 4096;
  short* XqT   = (short*)ws;                 ws += (long)Bsz * HW * KIN * 2;
  short* XkT   = (short*)ws;                 ws += (long)Bsz * HW * KIN * 2;
  short* Wt0   = (short*)ws;                 ws += (long)KOUT * KIN * 2;
  short* Wt1   = (short*)ws;                 ws += (long)KOUT * KIN * 2;
  short* Wt2   = (short*)ws;                 ws += (long)KOUT * KIN * 2;
  short* Wt3   = (short*)ws;                 ws += (long)Cc * CH3 * 2;
  short* qTb   = (short*)ws;                 ws += (long)Bsz * HW * KOUT * 2;
  short* kTb   = (short*)ws;                 ws += (long)Bsz * HW * KOUT * 2;
  short* vb    = (short*)ws;                 ws += (long)Bsz * KOUT * HW * 2;
  short* hhT   = (short*)ws;                 ws += (long)Bsz * HW * CH3 * 2;

  k_pre<<<896, 256, 0, stream>>>(x, W0, W1, W2, W3, Wt0, Wt1, Wt2, Wt3, stats);
  k_build_xt<<<dim3(16, 16), 256, 0, stream>>>(x, q_cond, k_a, k_b, gsc, gbi,
                                               stats, XqT, XkT);
  k_gemm_qkv<<<dim3(4, 8, 48), 256, 0, stream>>>(
      XqT, XkT, Wt0, Wt1, Wt2, b0, b1, b2, qTb, kTb, vb);
  k_attn<<<dim3(8, 96), 512, 0, stream>>>(qTb, kTb, vb, hhT);
  k_gemm_final<<<dim3(16, 2, 16), 256, 0, stream>>>(Wt3, hhT, x, b3, out);
}

// Round 11
// 201.688 us; speedup vs baseline: 1.2845x; 1.0191x over previous
//
#include <hip/hip_runtime.h>
#include <hip/hip_bf16.h>

typedef __attribute__((ext_vector_type(8))) short short8;
typedef __attribute__((ext_vector_type(4))) short short4v;
typedef __attribute__((ext_vector_type(4))) float f32x4;

__device__ inline short f2bf(float f) {
  __hip_bfloat16 h = __float2bfloat16(f);
  return __builtin_bit_cast(short, h);
}

__device__ inline f32x4 mfma16(short8 a, short8 b, f32x4 c) {
  return __builtin_amdgcn_mfma_f32_16x16x32_bf16(a, b, c, 0, 0, 0);
}

// ---------------- constants ----------------
#define Bsz 16
#define Cc 128
#define HW 1024
#define NHh 4
#define CONDc 32
#define KIN 160      // C + COND
#define XCH 192      // q_cs(32) | h(128) | k_cs(32)
#define KOUT 512     // C * NH
#define CH3 768      // (NH+2)*C
// 1/sqrt(128) * log2(e): QK^T scores in log2 domain -> P = exp2(s - m)
#define SCALE_Q2 0.12751742f

// ---------------- merged: groupnorm stats + weight transpose/bf16 ----------------
// Wt0[ko][c] matches X channels 0..159  = [q_cs|h] : c<32 -> W0 row c+128, else W0 row c-32
// Wt1/Wt2[ko][c] match X channels 32..191 = [h|k_cs]: plain W row c
__global__ __launch_bounds__(256) void k_pre(
    const float* __restrict__ x,
    const float* __restrict__ W0, const float* __restrict__ W1,
    const float* __restrict__ W2, const float* __restrict__ W3,
    short* __restrict__ Wt0, short* __restrict__ Wt1,
    short* __restrict__ Wt2, short* __restrict__ Wt3,
    float* __restrict__ stats) {
  int bx = blockIdx.x;
  if (bx < 512) {
    int b = bx >> 5, g = bx & 31;
    int tid = threadIdx.x, lane = tid & 63, wid = tid >> 6;
    long base = ((long)b * Cc + g * 4) * HW;
    float s = 0.f, sq = 0.f;
#pragma unroll
    for (int i = 0; i < 16; i++) {
      float v = x[base + tid + i * 256];
      s += v; sq += v * v;
    }
#pragma unroll
    for (int d = 1; d < 64; d <<= 1) {
      s += __shfl_xor(s, d);
      sq += __shfl_xor(sq, d);
    }
    __shared__ float ls[8];
    if (lane == 0) { ls[wid] = s; ls[wid + 4] = sq; }
    __syncthreads();
    if (tid == 0) {
      float ts = ls[0] + ls[1] + ls[2] + ls[3];
      float tq = ls[4] + ls[5] + ls[6] + ls[7];
      float mu = ts / 4096.f;
      float var = tq / 4096.f - mu * mu;
      var = var < 0.f ? 0.f : var;
      stats[(b * 32 + g) * 2] = mu;
      stats[(b * 32 + g) * 2 + 1] = rsqrtf(var + 1e-6f);
    }
  } else {
    int i = (bx - 512) * 256 + threadIdx.x;
    if (i < KOUT * KIN) {
      int ko = i / KIN, c = i % KIN;
      int c0 = (c < 32) ? (c + 128) : (c - 32);
      Wt0[i] = f2bf(W0[c0 * KOUT + ko]);
      Wt1[i] = f2bf(W1[c * KOUT + ko]);
      Wt2[i] = f2bf(W2[c * KOUT + ko]);
    }
    if (i < Cc * CH3) {
      int ko = i / CH3, ch = i % CH3;
      Wt3[i] = f2bf(W3[ch * Cc + ko]);
    }
  }
}

// ---------------- GN apply + concat -> X [b][hw][192] = [q_cs|h|k_cs] bf16 ----------------
// LDS xs[64][192] with 16B-slot XOR swizzle (slot ^= (row>>2)&7) to break the
// all-lanes-same-bank transpose-store pattern (row stride 384B == 0 mod 128B).
__device__ inline int xswz(int row, int bytecol) {
  return row * 384 + (bytecol ^ ((((row) >> 2) & 7) << 4));
}

__global__ __launch_bounds__(256) void k_build_xt(
    const float* __restrict__ x, const float* __restrict__ q_cond,
    const float* __restrict__ k_a, const float* __restrict__ k_b,
    const float* __restrict__ gsc, const float* __restrict__ gbi,
    const float* __restrict__ stats,
    short* __restrict__ X) {
  int b = blockIdx.y, hw0 = blockIdx.x * 64, tid = threadIdx.x;
  __shared__ char xs[64 * 384];
  // h part -> cols 32..159
#pragma unroll
  for (int i = 0; i < 8; i++) {
    int ci = tid + i * 256;
    int c = ci >> 4, hwo = (ci & 15) * 4;
    float4 xv = *(const float4*)(x + ((long)b * Cc + c) * HW + hw0 + hwo);
    int g = c >> 2;
    float mu = stats[(b * 32 + g) * 2];
    float rs = stats[(b * 32 + g) * 2 + 1];
    float sc = gsc[c] * rs;
    float bi = gbi[c] - mu * sc;
    int col = (32 + c) * 2;
    *(short*)(xs + xswz(hwo + 0, col)) = f2bf(xv.x * sc + bi);
    *(short*)(xs + xswz(hwo + 1, col)) = f2bf(xv.y * sc + bi);
    *(short*)(xs + xswz(hwo + 2, col)) = f2bf(xv.z * sc + bi);
    *(short*)(xs + xswz(hwo + 3, col)) = f2bf(xv.w * sc + bi);
  }
  // cond parts: q_cs -> cols 0..31, k_cs -> cols 160..191
#pragma unroll
  for (int i = 0; i < 2; i++) {
    int ci = tid + i * 256;
    int cc = ci >> 4, hwo = (ci & 15) * 4;
    long src = ((long)(b >> 1) * CONDc + cc) * HW + hw0 + hwo;
    float4 qv = *(const float4*)(q_cond + src);
    const float* ks = (b & 1) ? k_b : k_a;
    float4 kv = *(const float4*)(ks + src);
    int colq = cc * 2, colk = (160 + cc) * 2;
    *(short*)(xs + xswz(hwo + 0, colq)) = f2bf(qv.x);
    *(short*)(xs + xswz(hwo + 1, colq)) = f2bf(qv.y);
    *(short*)(xs + xswz(hwo + 2, colq)) = f2bf(qv.z);
    *(short*)(xs + xswz(hwo + 3, colq)) = f2bf(qv.w);
    *(short*)(xs + xswz(hwo + 0, colk)) = f2bf(kv.x);
    *(short*)(xs + xswz(hwo + 1, colk)) = f2bf(kv.y);
    *(short*)(xs + xswz(hwo + 2, colk)) = f2bf(kv.z);
    *(short*)(xs + xswz(hwo + 3, colk)) = f2bf(kv.w);
  }
  __syncthreads();
  // write out: 64 rows x 24 chunks of 16B
#pragma unroll
  for (int i = 0; i < 6; i++) {
    int ci = tid + i * 256;
    int row = ci / 24, ch = (ci % 24) * 8;
    long dst = ((long)b * HW + hw0 + row) * XCH + ch;
    *(short8*)(X + dst) = *(const short8*)(xs + xswz(row, ch * 2));
  }
}

// ---------------- merged QKV GEMM (shared X, reg-prefetch staging) ----------------
__device__ inline int gswz(int row, int kb) {
  return row * 64 + (kb ^ (((row >> 1) & 3) << 4));
}

__global__ __launch_bounds__(256) void k_gemm_qkv(
    const short* __restrict__ X,
    const short* __restrict__ Wt0, const short* __restrict__ Wt1,
    const short* __restrict__ Wt2,
    const float* __restrict__ b0v, const float* __restrict__ b1v,
    const float* __restrict__ b2v,
    short* __restrict__ qTb, short* __restrict__ kTb, short* __restrict__ vb) {
  int z = blockIdx.z, which = z >> 4, b = z & 15;
  const short* A;
  const short* Bm;
  long lda, ldb;
  short* D;
  const float* bias;
  float scale = 1.f;
  int m0, n0, ldD, bias_m = 0;
  if (which == 0) {
    A = X + (long)b * HW * XCH; lda = XCH;           // ch 0..159 = [q_cs|h]
    Bm = Wt0; ldb = KIN;
    D = qTb + (long)b * HW * KOUT;
    bias = b0v; scale = SCALE_Q2;
    m0 = blockIdx.y * 128; n0 = blockIdx.x * 128; ldD = KOUT;
  } else if (which == 1) {
    A = X + (long)b * HW * XCH + 32; lda = XCH;      // ch 32..191 = [h|k_cs]
    Bm = Wt1; ldb = KIN;
    D = kTb + (long)b * HW * KOUT;
    bias = b1v;
    m0 = blockIdx.y * 128; n0 = blockIdx.x * 128; ldD = KOUT;
  } else {
    A = Wt2; lda = KIN;
    Bm = X + (long)b * HW * XCH + 32; ldb = XCH;
    D = vb + (long)b * KOUT * HW;
    bias = b2v; bias_m = 1;
    m0 = blockIdx.x * 128; n0 = blockIdx.y * 128; ldD = HW;
  }
  int tid = threadIdx.x, lane = tid & 63, wid = tid >> 6;
  int wm = (wid >> 1) * 64, wn = (wid & 1) * 64;
  int lm = lane & 15, kg = lane >> 4;
  __shared__ short lA[128 * 32];
  __shared__ short lB[128 * 32];
  int row_[2], kb_[2];
  const short* asrc[2];
  const short* bsrc[2];
#pragma unroll
  for (int i = 0; i < 2; i++) {
    int ci = tid + i * 256;
    row_[i] = ci >> 2; kb_[i] = (ci & 3) * 16;
    asrc[i] = A + (long)(m0 + row_[i]) * lda + (kb_[i] >> 1);
    bsrc[i] = Bm + (long)(n0 + row_[i]) * ldb + (kb_[i] >> 1);
  }
  short8 ar[2], br[2];
#pragma unroll
  for (int i = 0; i < 2; i++) {
    ar[i] = *(const short8*)(asrc[i]);
    br[i] = *(const short8*)(bsrc[i]);
  }
  f32x4 acc[4][4] = {};
  for (int k0 = 0; k0 < KIN; k0 += 32) {
    __syncthreads();
#pragma unroll
    for (int i = 0; i < 2; i++) {
      *(short8*)((char*)lA + gswz(row_[i], kb_[i])) = ar[i];
      *(short8*)((char*)lB + gswz(row_[i], kb_[i])) = br[i];
    }
    if (k0 + 32 < KIN) {
#pragma unroll
      for (int i = 0; i < 2; i++) {
        ar[i] = *(const short8*)(asrc[i] + k0 + 32);
        br[i] = *(const short8*)(bsrc[i] + k0 + 32);
      }
    }
    __syncthreads();
    short8 af[4], bfr[4];
    int kb = kg * 16;
#pragma unroll
    for (int t = 0; t < 4; t++) {
      af[t] = *(const short8*)((char*)lA + gswz(wm + t * 16 + lm, kb));
      bfr[t] = *(const short8*)((char*)lB + gswz(wn + t * 16 + lm, kb));
    }
#pragma unroll
    for (int mt = 0; mt < 4; mt++)
#pragma unroll
      for (int nt = 0; nt < 4; nt++)
        acc[mt][nt] = mfma16(af[mt], bfr[nt], acc[mt][nt]);
  }
#pragma unroll
  for (int mt = 0; mt < 4; mt++)
#pragma unroll
    for (int nt = 0; nt < 4; nt++) {
      f32x4 c = acc[mt][nt];
      int n = n0 + wn + nt * 16 + lm;
#pragma unroll
      for (int r = 0; r < 4; r++) {
        int m = m0 + wm + mt * 16 + kg * 4 + r;
        float val = c[r] + bias[bias_m ? m : n];
        val *= scale;
        D[(long)m * ldD + n] = f2bf(val);
      }
    }
}

// ---------------- final GEMM: out = x + hhT*Wt3 + b3, BK=64 (12 stages) ----------------
// LDS rows 128B, swizzle (row&7)<<4 -> 2-way on b128 fragment reads.
__device__ inline int fswz(int row, int kb) {
  return row * 128 + (kb ^ ((row & 7) << 4));
}

__global__ __launch_bounds__(256) void k_gemm_final(
    const short* __restrict__ A,      // Wt3 [128][768]
    const short* __restrict__ Ball,   // hhT [16][1024][768]
    const float* __restrict__ x, const float* __restrict__ bias,
    float* __restrict__ out) {
  int b = blockIdx.z;
  const short* B = Ball + (long)b * HW * CH3;
  int m0 = blockIdx.y * 64, n0 = blockIdx.x * 64;
  int tid = threadIdx.x, lane = tid & 63, wid = tid >> 6;
  int wm = (wid >> 1) * 32, wn = (wid & 1) * 32;
  int lm = lane & 15, kg = lane >> 4;
  __shared__ short lA[64 * 64];
  __shared__ short lB[64 * 64];
  // 512 chunks per operand (64 rows x 8 chunks), 2 per thread
  int row_[2], kb_[2];
  const short* asrc[2];
  const short* bsrc[2];
#pragma unroll
  for (int i = 0; i < 2; i++) {
    int ci = tid + i * 256;
    row_[i] = ci >> 3; kb_[i] = (ci & 7) * 16;
    asrc[i] = A + (long)(m0 + row_[i]) * CH3 + (kb_[i] >> 1);
    bsrc[i] = B + (long)(n0 + row_[i]) * CH3 + (kb_[i] >> 1);
  }
  short8 ar[2], br[2];
#pragma unroll
  for (int i = 0; i < 2; i++) {
    ar[i] = *(const short8*)(asrc[i]);
    br[i] = *(const short8*)(bsrc[i]);
  }
  f32x4 acc[2][2] = {};
  for (int k0 = 0; k0 < CH3; k0 += 64) {
    __syncthreads();
#pragma unroll
    for (int i = 0; i < 2; i++) {
      *(short8*)((char*)lA + fswz(row_[i], kb_[i])) = ar[i];
      *(short8*)((char*)lB + fswz(row_[i], kb_[i])) = br[i];
    }
    if (k0 + 64 < CH3) {
#pragma unroll
      for (int i = 0; i < 2; i++) {
        ar[i] = *(const short8*)(asrc[i] + k0 + 64);
        br[i] = *(const short8*)(bsrc[i] + k0 + 64);
      }
    }
    __syncthreads();
#pragma unroll
    for (int ks = 0; ks < 2; ks++) {
      int kb = ks * 64 + kg * 16;
      short8 af[2], bfr[2];
#pragma unroll
      for (int t = 0; t < 2; t++) {
        af[t] = *(const short8*)((char*)lA + fswz(wm + t * 16 + lm, kb));
        bfr[t] = *(const short8*)((char*)lB + fswz(wn + t * 16 + lm, kb));
      }
#pragma unroll
      for (int mt = 0; mt < 2; mt++)
#pragma unroll
        for (int nt = 0; nt < 2; nt++)
          acc[mt][nt] = mfma16(af[mt], bfr[nt], acc[mt][nt]);
    }
  }
#pragma unroll
  for (int mt = 0; mt < 2; mt++)
#pragma unroll
    for (int nt = 0; nt < 2; nt++) {
      f32x4 c = acc[mt][nt];
      int n = n0 + wn + nt * 16 + lm;
#pragma unroll
      for (int r = 0; r < 4; r++) {
        int m = m0 + wm + mt * 16 + kg * 4 + r;
        float val = c[r] + bias[m];
        long oidx = ((long)b * Cc + m) * HW + n;
        out[oidx] = x[oidx] + val;
      }
    }
}

// ---------------- fused flash attention: 8 waves, KVBLK=64, reg-prefetch (proven) ----------------
__global__ __launch_bounds__(512) void k_attn(
    const short* __restrict__ qT, const short* __restrict__ kT,
    const short* __restrict__ v, short* __restrict__ hhT) {
  int flat = blockIdx.y * 8 + blockIdx.x;
  int idx = flat >> 3;
  int p = (flat & 7) * 12 + (idx >> 3);   // 12 problems per XCD
  int q0 = (idx & 7) * 128;               // 8 q-tiles of 128 rows

  int b4 = p / 24, rem = p % 24, j = rem >> 2, e = rem & 3;
  static const int qsl[6] = {0, 1, 2, 3, 0, 2};
  static const int kvl[6] = {1, 0, 3, 2, 2, 0};
  int bq = b4 * 4 + qsl[j];
  int bkv = b4 * 4 + kvl[j];
  int midx = 4 * j + e;
  int bo = b4 * 4 + midx / 6;
  int chb = (midx % 6) * Cc;
  int tid = threadIdx.x, lane = tid & 63, wid = tid >> 6;
  int lm = lane & 15, kg = lane >> 4;

  __shared__ char lK[64 * 256];
  __shared__ char lV[128 * 128];
  __shared__ char lP[8][2048];

  short8 qf[4];
  const short* qbase =
      qT + ((long)bq * HW + q0 + wid * 16 + lm) * KOUT + e * Cc + kg * 8;
#pragma unroll
  for (int ks = 0; ks < 4; ks++) qf[ks] = *(const short8*)(qbase + ks * 32);

  int krow[2], kcb[2], vrow[2], vkb[2];
  const short* kgsrc[2];
  const short* vgsrc[2];
#pragma unroll
  for (int i = 0; i < 2; i++) {
    int ci = tid + i * 512;
    krow[i] = ci >> 4; kcb[i] = (ci & 15) * 16;
    vrow[i] = ci >> 3; vkb[i] = (ci & 7) * 16;
    kgsrc[i] = kT + ((long)bkv * HW + krow[i]) * KOUT + e * Cc + (kcb[i] >> 1);
    vgsrc[i] = v + ((long)bkv * KOUT + e * Cc + vrow[i]) * HW + (vkb[i] >> 1);
  }

  short8 kr[2], vr[2];
#pragma unroll
  for (int i = 0; i < 2; i++) {
    kr[i] = *(const short8*)(kgsrc[i]);
    vr[i] = *(const short8*)(vgsrc[i]);
  }

  float mrow = -3e38f, lsum = 0.f;
  f32x4 oacc[8] = {};

  for (int kvt = 0; kvt < 16; kvt++) {
    __syncthreads();
#pragma unroll
    for (int i = 0; i < 2; i++) {
      *(short8*)(lK + krow[i] * 256 + (kcb[i] ^ ((krow[i] & 7) << 4))) = kr[i];
      *(short8*)(lV + vrow[i] * 128 + (vkb[i] ^ ((vrow[i] & 7) << 4))) = vr[i];
    }
    if (kvt < 15) {
      int kvn = (kvt + 1) * 64;
#pragma unroll
      for (int i = 0; i < 2; i++) {
        kr[i] = *(const short8*)(kgsrc[i] + (long)kvn * KOUT);
        vr[i] = *(const short8*)(vgsrc[i] + kvn);
      }
    }
    __syncthreads();
    f32x4 s[4] = {};
    __builtin_amdgcn_s_setprio(1);
#pragma unroll
    for (int ks = 0; ks < 4; ks++) {
      int cbyte = ks * 64 + kg * 16;
#pragma unroll
      for (int nt = 0; nt < 4; nt++) {
        int row = nt * 16 + lm;
        short8 kf = *(const short8*)(lK + row * 256 + (cbyte ^ ((row & 7) << 4)));
        s[nt] = mfma16(kf, qf[ks], s[nt]);
      }
    }
    __builtin_amdgcn_s_setprio(0);
    float mx = -3e38f;
#pragma unroll
    for (int nt = 0; nt < 4; nt++)
#pragma unroll
      for (int r = 0; r < 4; r++) mx = fmaxf(mx, s[nt][r]);
    mx = fmaxf(mx, __shfl_xor(mx, 16));
    mx = fmaxf(mx, __shfl_xor(mx, 32));
    if (mx > mrow + 8.f) {
      float corr = exp2f(mrow - mx);
      mrow = mx;
      lsum *= corr;
#pragma unroll
      for (int ct = 0; ct < 8; ct++) oacc[ct] *= corr;
    }
#pragma unroll
    for (int nt = 0; nt < 4; nt++)
#pragma unroll
      for (int r = 0; r < 4; r++) {
        float pv = exp2f(s[nt][r] - mrow);
        s[nt][r] = pv;
        lsum += pv;
      }
#pragma unroll
    for (int nt = 0; nt < 4; nt++) {
      short4v pk;
#pragma unroll
      for (int r = 0; r < 4; r++) pk[r] = f2bf(s[nt][r]);
      int kvb = (nt * 16 + kg * 4) * 2;
      *(short4v*)(lP[wid] + lm * 128 + (kvb ^ ((lm & 7) << 4))) = pk;
    }
    __builtin_amdgcn_s_setprio(1);
#pragma unroll
    for (int ks2 = 0; ks2 < 2; ks2++) {
      int kvbyte = ks2 * 64 + kg * 16;
      short8 pf = *(const short8*)(lP[wid] + lm * 128 + (kvbyte ^ ((lm & 7) << 4)));
#pragma unroll
      for (int ct = 0; ct < 8; ct++) {
        int row = ct * 16 + lm;
        short8 vf = *(const short8*)(lV + row * 128 + (kvbyte ^ ((row & 7) << 4)));
        oacc[ct] = mfma16(vf, pf, oacc[ct]);
      }
    }
    __builtin_amdgcn_s_setprio(0);
  }
  lsum += __shfl_xor(lsum, 16);
  lsum += __shfl_xor(lsum, 32);
  float inv = 1.f / lsum;
  long obase = ((long)bo * HW + q0 + wid * 16 + lm) * CH3 + chb + kg * 4;
#pragma unroll
  for (int ct = 0; ct < 8; ct++) {
    short4v pk;
#pragma unroll
    for (int r = 0; r < 4; r++) pk[r] = f2bf(oacc[ct][r] * inv);
    *(short4v*)(hhT + obase + ct * 16) = pk;
  }
}

// ---------------- launcher ----------------
extern "C" void kernel_launch(void* const* d_in, const int* in_sizes, int n_in,
                              void* d_out, int out_size, void* d_ws, size_t ws_size,
                              hipStream_t stream) {
  const float* x      = (const float*)d_in[0];
  const float* q_cond = (const float*)d_in[1];
  const float* k_a    = (const float*)d_in[2];
  const float* k_b    = (const float*)d_in[3];
  const float* gsc    = (const float*)d_in[4];
  const float* gbi    = (const float*)d_in[5];
  const float* W0     = (const float*)d_in[6];
  const float* b0     = (const float*)d_in[7];
  const float* W1     = (const float*)d_in[8];
  const float* b1     = (const float*)d_in[9];
  const float* W2     = (const float*)d_in[10];
  const float* b2     = (const float*)d_in[11];
  const float* W3     = (const float*)d_in[12];
  const float* b3     = (const float*)d_in[13];
  float* out = (float*)d_out;

  char* ws = (char*)d_ws;
  float* stats = (float*)ws;                 ws += 4096;
  short* Xbuf  = (short*)ws;                 ws += (long)Bsz * HW * XCH * 2;
  short* Wt0   = (short*)ws;                 ws += (long)KOUT * KIN * 2;
  short* Wt1   = (short*)ws;                 ws += (long)KOUT * KIN * 2;
  short* Wt2   = (short*)ws;                 ws += (long)KOUT * KIN * 2;
  short* Wt3   = (short*)ws;                 ws += (long)Cc * CH3 * 2;
  short* qTb   = (short*)ws;                 ws += (long)Bsz * HW * KOUT * 2;
  short* kTb   = (short*)ws;                 ws += (long)Bsz * HW * KOUT * 2;
  short* vb    = (short*)ws;                 ws += (long)Bsz * KOUT * HW * 2;
  short* hhT   = (short*)ws;                 ws += (long)Bsz * HW * CH3 * 2;

  k_pre<<<896, 256, 0, stream>>>(x, W0, W1, W2, W3, Wt0, Wt1, Wt2, Wt3, stats);
  k_build_xt<<<dim3(16, 16), 256, 0, stream>>>(x, q_cond, k_a, k_b, gsc, gbi,
                                               stats, Xbuf);
  k_gemm_qkv<<<dim3(4, 8, 48), 256, 0, stream>>>(
      Xbuf, Wt0, Wt1, Wt2, b0, b1, b2, qTb, kTb, vb);
  k_attn<<<dim3(8, 96), 512, 0, stream>>>(qTb, kTb, vb, hhT);
  k_gemm_final<<<dim3(16, 2, 16), 256, 0, stream>>>(Wt3, hhT, x, b3, out);
}